// Round 8
// baseline (226.100 us; speedup 1.0000x reference)
//
#include <hip/hip_runtime.h>
#include <hip/hip_bf16.h>

// Problem constants
#define BB 2
#define SS 1024
#define DD 1024
#define NH 16
#define DH 64
#define MM 8
#define RR 128
#define NN 256
#define NT (BB*SS)          // 2048 tokens

using bf16 = __hip_bfloat16;

typedef __attribute__((ext_vector_type(8))) short short8;   // 8 bf16 (4 VGPRs) MFMA A/B frag
typedef __attribute__((ext_vector_type(4))) short short4v;  // 8-byte unit
typedef __attribute__((ext_vector_type(4))) float f32x4;    // MFMA C/D frag

__device__ __forceinline__ void stf(float* p, size_t i, float v) { p[i] = v; }
__device__ __forceinline__ void stf(bf16* p, size_t i, float v) { p[i] = __float2bfloat16(v); }

// async 16B global->LDS (lane i lands at ldsbase + i*16; ldsbase wave-uniform)
#define GLD16(g, l) __builtin_amdgcn_global_load_lds( \
    (const __attribute__((address_space(1))) void*)(g), \
    (__attribute__((address_space(3))) void*)(l), 16, 0, 0)

// Load 8 bf16 (as shorts) from LDS via two 8B reads (base only 8B-aligned).
__device__ __forceinline__ short8 lds_load8(const short* p) {
    short4v a = *(const short4v*)p;
    short4v b = *(const short4v*)(p + 4);
    short8 r;
    r[0] = a[0]; r[1] = a[1]; r[2] = a[2]; r[3] = a[3];
    r[4] = b[0]; r[5] = b[1]; r[6] = b[2]; r[7] = b[3];
    return r;
}

// ---------------- MFMA GEMM, 64x128 tile, z-batched ----------------
// C[M,N] = A[M,K] @ Bt[N,K]^T, bf16 K-major. 4 waves (2x2), wave = 32x64
// (2x4 16x16x32 frags). Per-z A/Bt/C/N with early-exit for n0 >= N[z].
struct GemmZ {
    const bf16* A[5];
    const bf16* Bt[5];
    void* C[5];
    int N[5];
};

template <typename TC, int TAG>
__global__ __launch_bounds__(256) void mfma_gemm_64z(GemmZ P, int Kdim) {
    const int z = blockIdx.z;
    const int Nz = P.N[z];
    const int n0 = blockIdx.x * 128;
    if (n0 >= Nz) return;
    const bf16* __restrict__ A  = P.A[z];
    const bf16* __restrict__ Bt = P.Bt[z];
    TC* __restrict__ C = (TC*)P.C[z];

    const int tid = threadIdx.x;
    const int wave = tid >> 6, lane = tid & 63;
    const int quad = lane >> 4, l15 = lane & 15;
    const int wr = wave >> 1, wc = wave & 1;
    const int m0 = blockIdx.y * 64;

    __shared__ bf16 As[64 * 32];
    __shared__ bf16 Bs[128 * 32];

    f32x4 acc[2][4];
#pragma unroll
    for (int i = 0; i < 2; ++i)
#pragma unroll
        for (int j = 0; j < 4; ++j) acc[i][j] = (f32x4)0.f;

    for (int k0 = 0; k0 < Kdim; k0 += 32) {
        __syncthreads();
        {   // A: 256 16B-chunks, one per thread
            const int L = wave * 64 + lane;
            const int row = L >> 2;
            const int gch = (L & 3) ^ ((row >> 1) & 3);   // XOR swizzle
            GLD16(A + (size_t)(m0 + row) * Kdim + k0 + gch * 8, &As[(wave * 64) * 8]);
        }
#pragma unroll
        for (int i = 0; i < 2; ++i) {   // B: 512 chunks
            const int L = i * 256 + wave * 64 + lane;
            const int row = L >> 2;
            const int gch = (L & 3) ^ ((row >> 1) & 3);
            GLD16(Bt + (size_t)(n0 + row) * Kdim + k0 + gch * 8, &Bs[(i * 256 + wave * 64) * 8]);
        }
        __syncthreads();   // vmcnt(0): tiles resident

        short8 aF[2], bF[4];
#pragma unroll
        for (int bi = 0; bi < 2; ++bi) {
            int m = wr * 32 + bi * 16 + l15;
            aF[bi] = *(const short8*)&As[(m * 4 + (quad ^ ((m >> 1) & 3))) * 8];
        }
#pragma unroll
        for (int bj = 0; bj < 4; ++bj) {
            int n = wc * 64 + bj * 16 + l15;
            bF[bj] = *(const short8*)&Bs[(n * 4 + (quad ^ ((n >> 1) & 3))) * 8];
        }
#pragma unroll
        for (int bi = 0; bi < 2; ++bi)
#pragma unroll
            for (int bj = 0; bj < 4; ++bj)
                acc[bi][bj] = __builtin_amdgcn_mfma_f32_16x16x32_bf16(aF[bi], bF[bj], acc[bi][bj], 0, 0, 0);
    }

#pragma unroll
    for (int bi = 0; bi < 2; ++bi)
#pragma unroll
        for (int bj = 0; bj < 4; ++bj)
#pragma unroll
            for (int r = 0; r < 4; ++r) {
                int row = m0 + wr * 32 + bi * 16 + quad * 4 + r;
                int col = n0 + wc * 64 + bj * 16 + l15;
                stf(C, (size_t)row * Nz + col, acc[bi][bj][r]);
            }
}

// ---------------- W_O GEMM with fused attention-half merge ----------------
// out[M=2048][N=1024] = A @ W_O^T(K-major), where A[s][k] is computed on the
// fly from split-kt partials: A = (O0*w0 + O1*w1) * inv per (token s, head k>>6).
// A-tile staged via VALU + ds_write (same swizzled LDS layout as GLD16 path,
// so fragment reads are unchanged). B staged via GLD16.
__global__ __launch_bounds__(256) void mfma_gemm_wo(
    const float* __restrict__ Opart, const float* __restrict__ ml,
    const bf16* __restrict__ Bt, float* __restrict__ C) {
    const int Kdim = 1024, Ndim = 1024;
    const int tid = threadIdx.x;
    const int wave = tid >> 6, lane = tid & 63;
    const int quad = lane >> 4, l15 = lane & 15;
    const int wr = wave >> 1, wc = wave & 1;
    const int m0 = blockIdx.y * 64;
    const int n0 = blockIdx.x * 128;

    __shared__ bf16 As[64 * 32];
    __shared__ bf16 Bs[128 * 32];

    // fixed per-thread A staging slot: LDS chunk L=tid
    const int arow = tid >> 2;
    const int agch = (tid & 3) ^ ((arow >> 1) & 3);
    const int s = m0 + arow;                  // token
    const int b = s >> 10, srem = s & 1023;
    const int qt = srem >> 6, rin = srem & 63;

    f32x4 acc[2][4];
#pragma unroll
    for (int i = 0; i < 2; ++i)
#pragma unroll
        for (int j = 0; j < 4; ++j) acc[i][j] = (f32x4)0.f;

    for (int k0 = 0; k0 < Kdim; k0 += 32) {
        __syncthreads();
        {   // ---- A tile: fused combine of the two kt-halves ----
            const int k = k0 + agch * 8;
            const int h = k >> 6;
            const int p0 = (b * 16 + h) * 16 + qt;
            const int p1 = 512 + p0;
            float m0v = ml[(size_t)p0 * 128 + rin], l0v = ml[(size_t)p0 * 128 + 64 + rin];
            float m1v = ml[(size_t)p1 * 128 + rin], l1v = ml[(size_t)p1 * 128 + 64 + rin];
            float ms = fmaxf(m0v, m1v);
            float w0 = __expf(m0v - ms), w1 = __expf(m1v - ms);
            float inv = 1.0f / (l0v * w0 + l1v * w1);
            const int col = k & 63;
            const float* o0 = Opart + (size_t)p0 * 4096 + rin * 64 + col;
            const float* o1 = Opart + (size_t)p1 * 4096 + rin * 64 + col;
            short st[8];
#pragma unroll
            for (int j = 0; j < 8; j += 4) {
                float4 a = *(const float4*)(o0 + j);
                float4 bb = *(const float4*)(o1 + j);
                bf16 t0 = __float2bfloat16((a.x * w0 + bb.x * w1) * inv); st[j]     = *(short*)&t0;
                bf16 t1 = __float2bfloat16((a.y * w0 + bb.y * w1) * inv); st[j + 1] = *(short*)&t1;
                bf16 t2 = __float2bfloat16((a.z * w0 + bb.z * w1) * inv); st[j + 2] = *(short*)&t2;
                bf16 t3 = __float2bfloat16((a.w * w0 + bb.w * w1) * inv); st[j + 3] = *(short*)&t3;
            }
            short* dst = (short*)&As[tid * 8];
            *(short4v*)dst = *(short4v*)&st[0];
            *(short4v*)(dst + 4) = *(short4v*)&st[4];
        }
#pragma unroll
        for (int i = 0; i < 2; ++i) {   // ---- B tile via GLD16 ----
            const int L = i * 256 + wave * 64 + lane;
            const int row = L >> 2;
            const int gch = (L & 3) ^ ((row >> 1) & 3);
            GLD16(Bt + (size_t)(n0 + row) * Kdim + k0 + gch * 8, &Bs[(i * 256 + wave * 64) * 8]);
        }
        __syncthreads();

        short8 aF[2], bF[4];
#pragma unroll
        for (int bi = 0; bi < 2; ++bi) {
            int m = wr * 32 + bi * 16 + l15;
            aF[bi] = *(const short8*)&As[(m * 4 + (quad ^ ((m >> 1) & 3))) * 8];
        }
#pragma unroll
        for (int bj = 0; bj < 4; ++bj) {
            int n = wc * 64 + bj * 16 + l15;
            bF[bj] = *(const short8*)&Bs[(n * 4 + (quad ^ ((n >> 1) & 3))) * 8];
        }
#pragma unroll
        for (int bi = 0; bi < 2; ++bi)
#pragma unroll
            for (int bj = 0; bj < 4; ++bj)
                acc[bi][bj] = __builtin_amdgcn_mfma_f32_16x16x32_bf16(aF[bi], bF[bj], acc[bi][bj], 0, 0, 0);
    }

#pragma unroll
    for (int bi = 0; bi < 2; ++bi)
#pragma unroll
        for (int bj = 0; bj < 4; ++bj)
#pragma unroll
            for (int r = 0; r < 4; ++r) {
                int row = m0 + wr * 32 + bi * 16 + quad * 4 + r;
                int col = n0 + wc * 64 + bj * 16 + l15;
                C[(size_t)row * Ndim + col] = acc[bi][bj][r];
            }
}

// ---------------- fused convert/transpose (f32 -> bf16) ----------------
struct ConvJobs {
    const float* src[9];
    bf16* dst[9];
    int K[9], R[9], G[9];
    int tEnd[9];   // cumulative tile counts
};

__global__ void convert_kernel(ConvJobs J) {
    __shared__ float tile[32][33];
    const int b = blockIdx.x;
    int j = 0;
    while (j < 8 && b >= J.tEnd[j]) ++j;
    const int local = b - (j > 0 ? J.tEnd[j - 1] : 0);
    const float* src = J.src[j];
    bf16* dst = J.dst[j];
    const int tid = threadIdx.x;

    if (J.G[j] == 0) {
        size_t base = (size_t)local * 4096 + (size_t)tid * 16;
        const float4* s4 = (const float4*)(src + base);
        short* d = (short*)(dst + base);
#pragma unroll
        for (int c = 0; c < 4; ++c) {
            float4 v = s4[c];
            short4v o;
            bf16 t0 = __float2bfloat16(v.x); o[0] = *(short*)&t0;
            bf16 t1 = __float2bfloat16(v.y); o[1] = *(short*)&t1;
            bf16 t2 = __float2bfloat16(v.z); o[2] = *(short*)&t2;
            bf16 t3 = __float2bfloat16(v.w); o[3] = *(short*)&t3;
            *(short4v*)(d + c * 4) = o;
        }
    } else {
        const int Kj = J.K[j], Rj = J.R[j];
        const int Rb = Rj >> 5, Kb = Kj >> 5;
        const int perG = Kb * Rb;
        const int g = local / perG;
        const int rem = local - g * perG;
        const int kb = rem / Rb, rb = rem - kb * Rb;
        const int tx = tid & 31, ty0 = tid >> 5;
        const float* s = src + ((size_t)(g * Kj + kb * 32) * Rj) + rb * 32 + tx;
#pragma unroll
        for (int p = 0; p < 4; ++p)
            tile[ty0 + p * 8][tx] = s[(size_t)(ty0 + p * 8) * Rj];
        __syncthreads();
        bf16* dd = dst + ((size_t)(g * Rj + rb * 32) * Kj) + kb * 32 + tx;
#pragma unroll
        for (int p = 0; p < 4; ++p)
            dd[(size_t)(ty0 + p * 8) * Kj] = __float2bfloat16(tile[tx][ty0 + p * 8]);
    }
}

// ---------------- fused gates + combine + make_pre (shuffle softmax) -------
// One block per token. 3 softmaxes over 256 logits via wave shuffles:
// wave max/sum with __shfl_xor (no barrier), 32-lane segmented shuffles for
// the 8 group sums, cross-wave exchange through tiny LDS arrays. 4 barriers
// total (was ~60 with LDS trees). Math identical to reference ordering:
// raw[m]=s_m/total ; gate[m]=raw[m]/(sum raw + 1e-8).
__global__ void gate_combine(const bf16* __restrict__ logitsAll,
                             const bf16* __restrict__ allh,
                             bf16* __restrict__ preQ, bf16* __restrict__ preK,
                             bf16* __restrict__ preV) {
    const int t = blockIdx.x;
    const int n = threadIdx.x;   // 256
    const int wave = n >> 6, lane = n & 63;
    __shared__ float wred[3][4];
    __shared__ float sred[3][4];
    __shared__ float gred[3][8];

    float v[3], e[3];
#pragma unroll
    for (int z = 0; z < 3; ++z)
        v[z] = __bfloat162float(logitsAll[(size_t)z * NT * NN + (size_t)t * NN + n]);

    // wave max (6 shfl steps), cross-wave via LDS
    float mz[3];
#pragma unroll
    for (int z = 0; z < 3; ++z) {
        mz[z] = v[z];
#pragma unroll
        for (int off = 1; off <= 32; off <<= 1)
            mz[z] = fmaxf(mz[z], __shfl_xor(mz[z], off));
    }
    if (lane == 0) {
#pragma unroll
        for (int z = 0; z < 3; ++z) wred[z][wave] = mz[z];
    }
    __syncthreads();
    float gmax[3];
#pragma unroll
    for (int z = 0; z < 3; ++z)
        gmax[z] = fmaxf(fmaxf(wred[z][0], wred[z][1]), fmaxf(wred[z][2], wred[z][3]));

    // exp + wave sum
    float ws[3];
#pragma unroll
    for (int z = 0; z < 3; ++z) {
        e[z] = __expf(v[z] - gmax[z]);
        ws[z] = e[z];
#pragma unroll
        for (int off = 1; off <= 32; off <<= 1)
            ws[z] += __shfl_xor(ws[z], off);
    }
    if (lane == 0) {
#pragma unroll
        for (int z = 0; z < 3; ++z) sred[z][wave] = ws[z];
    }
    // group sums: 32 consecutive lanes (masks 1..16 stay within the half-wave)
    float gs[3];
#pragma unroll
    for (int z = 0; z < 3; ++z) {
        gs[z] = e[z];
#pragma unroll
        for (int off = 1; off <= 16; off <<= 1)
            gs[z] += __shfl_xor(gs[z], off);
    }
    __syncthreads();
    float total[3];
#pragma unroll
    for (int z = 0; z < 3; ++z)
        total[z] = sred[z][0] + sred[z][1] + sred[z][2] + sred[z][3];
    if ((n & 31) == 0) {
#pragma unroll
        for (int z = 0; z < 3; ++z) gred[z][n >> 5] = gs[z] / total[z];
    }
    __syncthreads();

    float gv[3][8];
#pragma unroll
    for (int z = 0; z < 3; ++z) {
        float tot = 0.f;
#pragma unroll
        for (int m = 0; m < 8; ++m) tot += gred[z][m];
        float inv = 1.0f / (tot + 1e-8f);
#pragma unroll
        for (int m = 0; m < 8; ++m) gv[z][m] = gred[z][m] * inv;
    }

    const int r0 = n & 127;
    const int half = n >> 7;
    const bf16* src_qk = allh + (size_t)t * 1024;
    const bf16* src_v  = allh + (size_t)NT * DD + (size_t)t * 1024;
    float hq = 0.f, hk = 0.f, hv = 0.f;
#pragma unroll
    for (int m = 0; m < 8; ++m) {
        float aqk = __bfloat162float(src_qk[m * 128 + r0]);
        float av  = __bfloat162float(src_v[m * 128 + r0]);
        hq += aqk * gv[0][m];
        hk += aqk * gv[1][m];
        hv += av  * gv[2][m];
    }
    __syncthreads();   // all allh_v reads complete before in-place preV writes
#pragma unroll
    for (int mm = 0; mm < 4; ++mm) {
        int m = half * 4 + mm;
        size_t o = (size_t)t * 1024 + m * 128 + r0;
        preQ[o] = __float2bfloat16(hq * gv[0][m]);
        preK[o] = __float2bfloat16(hk * gv[1][m]);
        preV[o] = __float2bfloat16(hv * gv[2][m]);
    }
}

// -------------------- Flash attention, split-kt (MFMA) --------------------
// Each (b,h,qt) is computed by TWO blocks: half0 kt in [0,h0), half1 [h0,qt+1)
// with h0 = ceil((qt+1)/2). Critical path <= 8 K-tile iterations. Partials
// (unnormalized O f32, m, l) go to workspace; merge fused into W_O GEMM.
#define LDK 68   // padded halfword stride for K/V/P LDS tiles

__global__ __launch_bounds__(256) void flash_attn_split(
    const bf16* __restrict__ Q, const bf16* __restrict__ K,
    const bf16* __restrict__ V, float* __restrict__ Opart,
    float* __restrict__ ml) {
    const int bx = blockIdx.x;
    const int c = bx & 511;
    const int second = bx >> 9;
    const int qt = second ? (c >> 5) : (15 - (c >> 5));
    const int half = second;
    const int bh = c & 31;
    const int b = bh >> 4;
    const int h = bh & 15;
    const int h0 = (qt + 2) >> 1;
    const int kt_lo = half ? h0 : 0;
    const int kt_hi = half ? (qt + 1) : h0;

    const int tid = threadIdx.x;
    const int wave = tid >> 6;
    const int lane = tid & 63;
    const int quad = lane >> 4;
    const int l15 = lane & 15;

    __shared__ short Ks[64 * LDK];        // Ks[kr][dh]
    __shared__ short Vt[64 * LDK];        // Vt[dh][kr]
    __shared__ short Ps[4 * 16 * LDK];    // per-wave P[m][kr]

    const int q_row = qt * 64 + wave * 16 + l15;
    const bf16* qptr = Q + (size_t)(b * SS + q_row) * DD + h * DH + quad * 8;
    short8 aq0 = *(const short8*)qptr;
    short8 aq1 = *(const short8*)(qptr + 32);

    float m_r[4], l_r[4];
    f32x4 o[4];
#pragma unroll
    for (int r = 0; r < 4; ++r) { m_r[r] = -3.0e38f; l_r[r] = 0.f; }
#pragma unroll
    for (int cc = 0; cc < 4; ++cc) o[cc] = (f32x4)0.f;

    const float scale = 0.125f;

    for (int kt = kt_lo; kt < kt_hi; ++kt) {
        const int kt0 = kt * 64;
        __syncthreads();
        {
            const int kr = tid >> 2;
            const int dhb = (tid & 3) * 16;
            const bf16* src = K + (size_t)(b * SS + kt0 + kr) * DD + h * DH + dhb;
            short4v v0 = *(const short4v*)(src);
            short4v v1 = *(const short4v*)(src + 4);
            short4v v2 = *(const short4v*)(src + 8);
            short4v v3 = *(const short4v*)(src + 12);
            short* dst = &Ks[kr * LDK + dhb];
            *(short4v*)(dst) = v0;
            *(short4v*)(dst + 4) = v1;
            *(short4v*)(dst + 8) = v2;
            *(short4v*)(dst + 12) = v3;
        }
        {
            const int krp = tid & 31;
            const int dhb = (tid >> 5) * 8;
            const bf16* s0 = V + (size_t)(b * SS + kt0 + 2 * krp) * DD + h * DH + dhb;
            short8 r0 = *(const short8*)s0;
            short8 r1 = *(const short8*)(s0 + DD);
#pragma unroll
            for (int i = 0; i < 8; ++i) {
                unsigned int pk = (unsigned short)r0[i] | ((unsigned int)(unsigned short)r1[i] << 16);
                *(unsigned int*)&Vt[(dhb + i) * LDK + 2 * krp] = pk;
            }
        }
        __syncthreads();

        f32x4 s[4];
#pragma unroll
        for (int cc = 0; cc < 4; ++cc) {
            short8 bk0 = lds_load8(&Ks[(cc * 16 + l15) * LDK + quad * 8]);
            short8 bk1 = lds_load8(&Ks[(cc * 16 + l15) * LDK + 32 + quad * 8]);
            f32x4 acc = (f32x4)0.f;
            acc = __builtin_amdgcn_mfma_f32_16x16x32_bf16(aq0, bk0, acc, 0, 0, 0);
            acc = __builtin_amdgcn_mfma_f32_16x16x32_bf16(aq1, bk1, acc, 0, 0, 0);
            s[cc] = acc;
        }

        const bool diag = (kt == qt);
#pragma unroll
        for (int cc = 0; cc < 4; ++cc) {
#pragma unroll
            for (int r = 0; r < 4; ++r) {
                float v = s[cc][r] * scale;
                if (diag) {
                    int row_rel = wave * 16 + quad * 4 + r;
                    int col_rel = cc * 16 + l15;
                    if (col_rel > row_rel) v = -3.0e38f;
                }
                s[cc][r] = v;
            }
        }

        float p[4][4];
        float alpha[4];
#pragma unroll
        for (int r = 0; r < 4; ++r) {
            float mx = fmaxf(fmaxf(s[0][r], s[1][r]), fmaxf(s[2][r], s[3][r]));
            mx = fmaxf(mx, __shfl_xor(mx, 1));
            mx = fmaxf(mx, __shfl_xor(mx, 2));
            mx = fmaxf(mx, __shfl_xor(mx, 4));
            mx = fmaxf(mx, __shfl_xor(mx, 8));
            float new_m = fmaxf(m_r[r], mx);
            alpha[r] = __expf(m_r[r] - new_m);
            float rs = 0.f;
#pragma unroll
            for (int cc = 0; cc < 4; ++cc) {
                float e = __expf(s[cc][r] - new_m);
                p[cc][r] = e;
                rs += e;
            }
            rs += __shfl_xor(rs, 1);
            rs += __shfl_xor(rs, 2);
            rs += __shfl_xor(rs, 4);
            rs += __shfl_xor(rs, 8);
            l_r[r] = l_r[r] * alpha[r] + rs;
            m_r[r] = new_m;
        }
#pragma unroll
        for (int cc = 0; cc < 4; ++cc)
#pragma unroll
            for (int r = 0; r < 4; ++r) o[cc][r] *= alpha[r];

        // P: C-layout -> wave-private LDS slab -> A-layout (no barrier needed)
        short* pw = &Ps[wave * 16 * LDK];
#pragma unroll
        for (int cc = 0; cc < 4; ++cc)
#pragma unroll
            for (int r = 0; r < 4; ++r) {
                bf16 hb = __float2bfloat16(p[cc][r]);
                pw[(quad * 4 + r) * LDK + cc * 16 + l15] = *(short*)&hb;
            }

        short8 ap0 = lds_load8(&pw[l15 * LDK + quad * 8]);
        short8 ap1 = lds_load8(&pw[l15 * LDK + 32 + quad * 8]);

#pragma unroll
        for (int cc = 0; cc < 4; ++cc) {
            short8 bv0 = lds_load8(&Vt[(cc * 16 + l15) * LDK + quad * 8]);
            short8 bv1 = lds_load8(&Vt[(cc * 16 + l15) * LDK + 32 + quad * 8]);
            o[cc] = __builtin_amdgcn_mfma_f32_16x16x32_bf16(ap0, bv0, o[cc], 0, 0, 0);
            o[cc] = __builtin_amdgcn_mfma_f32_16x16x32_bf16(ap1, bv1, o[cc], 0, 0, 0);
        }
    }

    // ---- write partials (unnormalized O, m, l) ----
    const int idx = (half * 32 + bh) * 16 + qt;
    float* ob = Opart + (size_t)idx * 4096;
#pragma unroll
    for (int cc = 0; cc < 4; ++cc)
#pragma unroll
        for (int r = 0; r < 4; ++r) {
            int row = wave * 16 + quad * 4 + r;
            ob[row * 64 + cc * 16 + l15] = o[cc][r];
        }
    if (l15 == 0) {
#pragma unroll
        for (int r = 0; r < 4; ++r) {
            int row = wave * 16 + quad * 4 + r;
            ml[(size_t)idx * 128 + row] = m_r[r];
            ml[(size_t)idx * 128 + 64 + row] = l_r[r];
        }
    }
}

extern "C" void kernel_launch(void* const* d_in, const int* in_sizes, int n_in,
                              void* d_out, int out_size, void* d_ws, size_t ws_size,
                              hipStream_t stream) {
    const float* x    = (const float*)d_in[0];
    const float* qk_f = (const float*)d_in[1];
    const float* qk_r = (const float*)d_in[2];
    const float* v_f  = (const float*)d_in[3];
    const float* v_r  = (const float*)d_in[4];
    const float* Wg_q = (const float*)d_in[5];
    const float* Wg_k = (const float*)d_in[6];
    const float* Wg_v = (const float*)d_in[7];
    const float* W_O  = (const float*)d_in[8];

    // Workspace (256 MiB proven by fill WRITE_SIZE). Layout:
    //  0..4    xb      -> preQ
    //  4..8    wg_bt(4..5.5)+pad    -> preK
    //  5.5..9.5 fbt    (dead after proj)
    //  8..12           -> Kb
    //  9.5..12.5 logits (dead after gate_combine)
    //  12..16          -> Vb
    //  16..18 qkr_bt | 18..20 vr_bt | 20..22 wo_bt (stable)
    //  32..48 Opart (f32 partials) | 48..48.5 ml
    // d_out: allh [0..8 MiB] -> preV in-place over allh_v -> Qb [0..4] -> f32 out
    char* w = (char*)d_ws;
    const size_t MB = 1 << 20;
    bf16* xb     = (bf16*)(w + 0);
    bf16* wg_bt  = (bf16*)(w + 4 * MB);
    bf16* fbt    = (bf16*)(w + (size_t)(5.5 * MB));
    bf16* logits = (bf16*)(w + (size_t)(9.5 * MB));
    bf16* qkr_bt = (bf16*)(w + 16 * MB);
    bf16* vr_bt  = (bf16*)(w + 18 * MB);
    bf16* wo_bt  = (bf16*)(w + 20 * MB);
    bf16* preQ   = (bf16*)(w + 0);
    bf16* preK   = (bf16*)(w + 4 * MB);
    bf16* Kb     = (bf16*)(w + 8 * MB);
    bf16* Vb     = (bf16*)(w + 12 * MB);
    float* Opart = (float*)(w + 32 * MB);     // 1024 * 4096 f32 = 16 MiB
    float* mlbuf = (float*)(w + 48 * MB);     // 1024 * 128 f32 = 0.5 MiB
    bf16* allh   = (bf16*)d_out;              // [2][2048][1024] bf16 = 8 MiB
    bf16* preV   = allh + (size_t)NT * DD;    // in-place over allh_v
    bf16* Qb     = (bf16*)d_out;              // over dead allh_qk
    float* out   = (float*)d_out;

    // 1) convert/transpose all inputs to bf16 (weights -> Bt[N][K])
    ConvJobs J;
    J.src[0] = qk_f; J.dst[0] = fbt;              J.K[0] = 1024; J.R[0] = 128;  J.G[0] = 8;
    J.src[1] = v_f;  J.dst[1] = fbt + 1024*1024;  J.K[1] = 1024; J.R[1] = 128;  J.G[1] = 8;
    J.src[2] = qk_r; J.dst[2] = qkr_bt;           J.K[2] = 1024; J.R[2] = 1024; J.G[2] = 1;
    J.src[3] = v_r;  J.dst[3] = vr_bt;            J.K[3] = 1024; J.R[3] = 1024; J.G[3] = 1;
    J.src[4] = W_O;  J.dst[4] = wo_bt;            J.K[4] = 1024; J.R[4] = 1024; J.G[4] = 1;
    J.src[5] = Wg_q; J.dst[5] = wg_bt;            J.K[5] = 1024; J.R[5] = 256;  J.G[5] = 1;
    J.src[6] = Wg_k; J.dst[6] = wg_bt + 256*1024; J.K[6] = 1024; J.R[6] = 256;  J.G[6] = 1;
    J.src[7] = Wg_v; J.dst[7] = wg_bt + 2*256*1024; J.K[7] = 1024; J.R[7] = 256; J.G[7] = 1;
    J.src[8] = x;    J.dst[8] = xb;               J.K[8] = 0;    J.R[8] = 0;    J.G[8] = 0;
    int tiles[9] = {1024, 1024, 1024, 1024, 1024, 256, 256, 256, 512};
    int cum = 0;
    for (int i = 0; i < 9; ++i) { cum += tiles[i]; J.tEnd[i] = cum; }
    convert_kernel<<<cum, 256, 0, stream>>>(J);

    // 2) all projections in ONE launch (z=5, 64x128 tiles -> 704 useful blocks)
    GemmZ Pp;
    Pp.A[0] = Pp.A[1] = Pp.A[2] = Pp.A[3] = Pp.A[4] = xb;
    Pp.Bt[0] = fbt;             Pp.Bt[1] = fbt + 1024*1024;
    Pp.Bt[2] = wg_bt;           Pp.Bt[3] = wg_bt + 256*1024;  Pp.Bt[4] = wg_bt + 2*256*1024;
    Pp.C[0] = allh;             Pp.C[1] = allh + (size_t)NT * DD;
    Pp.C[2] = logits;           Pp.C[3] = logits + (size_t)NT * NN;
    Pp.C[4] = logits + 2 * (size_t)NT * NN;
    Pp.N[0] = 1024; Pp.N[1] = 1024; Pp.N[2] = 256; Pp.N[3] = 256; Pp.N[4] = 256;
    mfma_gemm_64z<bf16, 0><<<dim3(8, 32, 5), 256, 0, stream>>>(Pp, DD);

    // 3) fused gates + combine + make_pre (shuffle softmax; preV in-place)
    gate_combine<<<NT, 256, 0, stream>>>(logits, allh, preQ, preK, preV);

    // 4) restore Q,K,V in ONE launch (z=3, 64x128 tiles -> 768 blocks)
    GemmZ Pr;
    Pr.A[0] = preQ; Pr.A[1] = preK; Pr.A[2] = preV;
    Pr.Bt[0] = qkr_bt; Pr.Bt[1] = qkr_bt; Pr.Bt[2] = vr_bt;
    Pr.C[0] = Qb; Pr.C[1] = Kb; Pr.C[2] = Vb;
    Pr.N[0] = Pr.N[1] = Pr.N[2] = 1024;
    Pr.A[3] = Pr.A[4] = nullptr; Pr.Bt[3] = Pr.Bt[4] = nullptr;
    Pr.C[3] = Pr.C[4] = nullptr; Pr.N[3] = Pr.N[4] = 0;
    mfma_gemm_64z<bf16, 1><<<dim3(8, 32, 3), 256, 0, stream>>>(Pr, DD);

    // 5) flash attention split-kt (1024 blocks, critical path 8 iters)
    flash_attn_split<<<dim3(1024), 256, 0, stream>>>(Qb, Kb, Vb, Opart, mlbuf);

    // 6) out = merged(attn) @ W_O — combine fused into A-operand staging
    mfma_gemm_wo<<<dim3(8, 32), 256, 0, stream>>>(Opart, mlbuf, wo_bt, out);
}

// Round 9
// 205.862 us; speedup vs baseline: 1.0983x; 1.0983x over previous
//
#include <hip/hip_runtime.h>
#include <hip/hip_bf16.h>

// Problem constants
#define BB 2
#define SS 1024
#define DD 1024
#define NH 16
#define DH 64
#define MM 8
#define RR 128
#define NN 256
#define NT (BB*SS)          // 2048 tokens

using bf16 = __hip_bfloat16;

typedef __attribute__((ext_vector_type(8))) short short8;   // 8 bf16 (4 VGPRs) MFMA A/B frag
typedef __attribute__((ext_vector_type(4))) short short4v;  // 8-byte unit
typedef __attribute__((ext_vector_type(4))) float f32x4;    // MFMA C/D frag

__device__ __forceinline__ void stf(float* p, size_t i, float v) { p[i] = v; }
__device__ __forceinline__ void stf(bf16* p, size_t i, float v) { p[i] = __float2bfloat16(v); }

// async 16B global->LDS (lane i lands at ldsbase + i*16; ldsbase wave-uniform)
#define GLD16(g, l) __builtin_amdgcn_global_load_lds( \
    (const __attribute__((address_space(1))) void*)(g), \
    (__attribute__((address_space(3))) void*)(l), 16, 0, 0)

// Load 8 bf16 (as shorts) from LDS via two 8B reads (base only 8B-aligned).
__device__ __forceinline__ short8 lds_load8(const short* p) {
    short4v a = *(const short4v*)p;
    short4v b = *(const short4v*)(p + 4);
    short8 r;
    r[0] = a[0]; r[1] = a[1]; r[2] = a[2]; r[3] = a[3];
    r[4] = b[0]; r[5] = b[1]; r[6] = b[2]; r[7] = b[3];
    return r;
}

// ---------------- MFMA GEMM, 64x128 tile, BK=64, z-batched ----------------
// C[M,N] = A[M,K] @ Bt[N,K]^T, bf16 K-major. 4 waves (2x2), wave = 32x64
// (2x4 16x16x32 frags), 16 MFMA per 2 barriers (m97 density). LDS 24 KB.
// Chunk = 16B = 8 bf16; 8 chunks/row; slot = chunk ^ ((row>>1)&7) XOR swizzle
// -> frag ds_read_b128 is 2-way bank-aliased (free, m136).
struct GemmZ {
    const bf16* A[5];
    const bf16* Bt[5];
    void* C[5];
    int N[5];
};

template <typename TC, int TAG>
__global__ __launch_bounds__(256) void mfma_gemm_64z(GemmZ P, int Kdim) {
    const int z = blockIdx.z;
    const int Nz = P.N[z];
    const int n0 = blockIdx.x * 128;
    if (n0 >= Nz) return;
    const bf16* __restrict__ A  = P.A[z];
    const bf16* __restrict__ Bt = P.Bt[z];
    TC* __restrict__ C = (TC*)P.C[z];

    const int tid = threadIdx.x;
    const int wave = tid >> 6, lane = tid & 63;
    const int quad = lane >> 4, l15 = lane & 15;
    const int wr = wave >> 1, wc = wave & 1;
    const int m0 = blockIdx.y * 64;

    __shared__ bf16 As[64 * 64];    // 8 KB
    __shared__ bf16 Bs[128 * 64];   // 16 KB

    f32x4 acc[2][4];
#pragma unroll
    for (int i = 0; i < 2; ++i)
#pragma unroll
        for (int j = 0; j < 4; ++j) acc[i][j] = (f32x4)0.f;

    for (int k0 = 0; k0 < Kdim; k0 += 64) {
        __syncthreads();
#pragma unroll
        for (int i = 0; i < 2; ++i) {   // A: 512 chunks
            const int L = i * 256 + wave * 64 + lane;
            const int row = L >> 3;
            const int gch = (L & 7) ^ ((row >> 1) & 7);
            GLD16(A + (size_t)(m0 + row) * Kdim + k0 + gch * 8, &As[(i * 256 + wave * 64) * 8]);
        }
#pragma unroll
        for (int i = 0; i < 4; ++i) {   // B: 1024 chunks
            const int L = i * 256 + wave * 64 + lane;
            const int row = L >> 3;
            const int gch = (L & 7) ^ ((row >> 1) & 7);
            GLD16(Bt + (size_t)(n0 + row) * Kdim + k0 + gch * 8, &Bs[(i * 256 + wave * 64) * 8]);
        }
        __syncthreads();   // vmcnt(0): tiles resident

#pragma unroll
        for (int kk = 0; kk < 2; ++kk) {
            short8 aF[2], bF[4];
#pragma unroll
            for (int bi = 0; bi < 2; ++bi) {
                int m = wr * 32 + bi * 16 + l15;
                int slot = (kk * 4 + quad) ^ ((m >> 1) & 7);
                aF[bi] = *(const short8*)&As[(m * 8 + slot) * 8];
            }
#pragma unroll
            for (int bj = 0; bj < 4; ++bj) {
                int n = wc * 64 + bj * 16 + l15;
                int slot = (kk * 4 + quad) ^ ((n >> 1) & 7);
                bF[bj] = *(const short8*)&Bs[(n * 8 + slot) * 8];
            }
#pragma unroll
            for (int bi = 0; bi < 2; ++bi)
#pragma unroll
                for (int bj = 0; bj < 4; ++bj)
                    acc[bi][bj] = __builtin_amdgcn_mfma_f32_16x16x32_bf16(aF[bi], bF[bj], acc[bi][bj], 0, 0, 0);
        }
    }

#pragma unroll
    for (int bi = 0; bi < 2; ++bi)
#pragma unroll
        for (int bj = 0; bj < 4; ++bj)
#pragma unroll
            for (int r = 0; r < 4; ++r) {
                int row = m0 + wr * 32 + bi * 16 + quad * 4 + r;
                int col = n0 + wc * 64 + bj * 16 + l15;
                stf(C, (size_t)row * Nz + col, acc[bi][bj][r]);
            }
}

// ---------------- MFMA GEMM, 64x128 tile, BK=64, single job (W_O) ----------
template <typename TC>
__global__ __launch_bounds__(256) void mfma_gemm_64(
    const bf16* __restrict__ A, const bf16* __restrict__ Bt, TC* __restrict__ C,
    int Kdim, int Ndim) {
    const int tid = threadIdx.x;
    const int wave = tid >> 6, lane = tid & 63;
    const int quad = lane >> 4, l15 = lane & 15;
    const int wr = wave >> 1, wc = wave & 1;
    const int m0 = blockIdx.y * 64;
    const int n0 = blockIdx.x * 128;

    __shared__ bf16 As[64 * 64];
    __shared__ bf16 Bs[128 * 64];

    f32x4 acc[2][4];
#pragma unroll
    for (int i = 0; i < 2; ++i)
#pragma unroll
        for (int j = 0; j < 4; ++j) acc[i][j] = (f32x4)0.f;

    for (int k0 = 0; k0 < Kdim; k0 += 64) {
        __syncthreads();
#pragma unroll
        for (int i = 0; i < 2; ++i) {
            const int L = i * 256 + wave * 64 + lane;
            const int row = L >> 3;
            const int gch = (L & 7) ^ ((row >> 1) & 7);
            GLD16(A + (size_t)(m0 + row) * Kdim + k0 + gch * 8, &As[(i * 256 + wave * 64) * 8]);
        }
#pragma unroll
        for (int i = 0; i < 4; ++i) {
            const int L = i * 256 + wave * 64 + lane;
            const int row = L >> 3;
            const int gch = (L & 7) ^ ((row >> 1) & 7);
            GLD16(Bt + (size_t)(n0 + row) * Kdim + k0 + gch * 8, &Bs[(i * 256 + wave * 64) * 8]);
        }
        __syncthreads();

#pragma unroll
        for (int kk = 0; kk < 2; ++kk) {
            short8 aF[2], bF[4];
#pragma unroll
            for (int bi = 0; bi < 2; ++bi) {
                int m = wr * 32 + bi * 16 + l15;
                int slot = (kk * 4 + quad) ^ ((m >> 1) & 7);
                aF[bi] = *(const short8*)&As[(m * 8 + slot) * 8];
            }
#pragma unroll
            for (int bj = 0; bj < 4; ++bj) {
                int n = wc * 64 + bj * 16 + l15;
                int slot = (kk * 4 + quad) ^ ((n >> 1) & 7);
                bF[bj] = *(const short8*)&Bs[(n * 8 + slot) * 8];
            }
#pragma unroll
            for (int bi = 0; bi < 2; ++bi)
#pragma unroll
                for (int bj = 0; bj < 4; ++bj)
                    acc[bi][bj] = __builtin_amdgcn_mfma_f32_16x16x32_bf16(aF[bi], bF[bj], acc[bi][bj], 0, 0, 0);
        }
    }

#pragma unroll
    for (int bi = 0; bi < 2; ++bi)
#pragma unroll
        for (int bj = 0; bj < 4; ++bj)
#pragma unroll
            for (int r = 0; r < 4; ++r) {
                int row = m0 + wr * 32 + bi * 16 + quad * 4 + r;
                int col = n0 + wc * 64 + bj * 16 + l15;
                stf(C, (size_t)row * Ndim + col, acc[bi][bj][r]);
            }
}

// ---------------- fused convert/transpose (f32 -> bf16) ----------------
struct ConvJobs {
    const float* src[9];
    bf16* dst[9];
    int K[9], R[9], G[9];
    int tEnd[9];   // cumulative tile counts
};

__global__ void convert_kernel(ConvJobs J) {
    __shared__ float tile[32][33];
    const int b = blockIdx.x;
    int j = 0;
    while (j < 8 && b >= J.tEnd[j]) ++j;
    const int local = b - (j > 0 ? J.tEnd[j - 1] : 0);
    const float* src = J.src[j];
    bf16* dst = J.dst[j];
    const int tid = threadIdx.x;

    if (J.G[j] == 0) {
        size_t base = (size_t)local * 4096 + (size_t)tid * 16;
        const float4* s4 = (const float4*)(src + base);
        short* d = (short*)(dst + base);
#pragma unroll
        for (int c = 0; c < 4; ++c) {
            float4 v = s4[c];
            short4v o;
            bf16 t0 = __float2bfloat16(v.x); o[0] = *(short*)&t0;
            bf16 t1 = __float2bfloat16(v.y); o[1] = *(short*)&t1;
            bf16 t2 = __float2bfloat16(v.z); o[2] = *(short*)&t2;
            bf16 t3 = __float2bfloat16(v.w); o[3] = *(short*)&t3;
            *(short4v*)(d + c * 4) = o;
        }
    } else {
        const int Kj = J.K[j], Rj = J.R[j];
        const int Rb = Rj >> 5, Kb = Kj >> 5;
        const int perG = Kb * Rb;
        const int g = local / perG;
        const int rem = local - g * perG;
        const int kb = rem / Rb, rb = rem - kb * Rb;
        const int tx = tid & 31, ty0 = tid >> 5;
        const float* s = src + ((size_t)(g * Kj + kb * 32) * Rj) + rb * 32 + tx;
#pragma unroll
        for (int p = 0; p < 4; ++p)
            tile[ty0 + p * 8][tx] = s[(size_t)(ty0 + p * 8) * Rj];
        __syncthreads();
        bf16* dd = dst + ((size_t)(g * Rj + rb * 32) * Kj) + kb * 32 + tx;
#pragma unroll
        for (int p = 0; p < 4; ++p)
            dd[(size_t)(ty0 + p * 8) * Kj] = __float2bfloat16(tile[tx][ty0 + p * 8]);
    }
}

// ---------------- fused gates + combine + make_pre (shuffle softmax) -------
__global__ void gate_combine(const bf16* __restrict__ logitsAll,
                             const bf16* __restrict__ allh,
                             bf16* __restrict__ preQ, bf16* __restrict__ preK,
                             bf16* __restrict__ preV) {
    const int t = blockIdx.x;
    const int n = threadIdx.x;   // 256
    const int wave = n >> 6, lane = n & 63;
    __shared__ float wred[3][4];
    __shared__ float sred[3][4];
    __shared__ float gred[3][8];

    float v[3], e[3];
#pragma unroll
    for (int z = 0; z < 3; ++z)
        v[z] = __bfloat162float(logitsAll[(size_t)z * NT * NN + (size_t)t * NN + n]);

    float mz[3];
#pragma unroll
    for (int z = 0; z < 3; ++z) {
        mz[z] = v[z];
#pragma unroll
        for (int off = 1; off <= 32; off <<= 1)
            mz[z] = fmaxf(mz[z], __shfl_xor(mz[z], off));
    }
    if (lane == 0) {
#pragma unroll
        for (int z = 0; z < 3; ++z) wred[z][wave] = mz[z];
    }
    __syncthreads();
    float gmax[3];
#pragma unroll
    for (int z = 0; z < 3; ++z)
        gmax[z] = fmaxf(fmaxf(wred[z][0], wred[z][1]), fmaxf(wred[z][2], wred[z][3]));

    float ws[3];
#pragma unroll
    for (int z = 0; z < 3; ++z) {
        e[z] = __expf(v[z] - gmax[z]);
        ws[z] = e[z];
#pragma unroll
        for (int off = 1; off <= 32; off <<= 1)
            ws[z] += __shfl_xor(ws[z], off);
    }
    if (lane == 0) {
#pragma unroll
        for (int z = 0; z < 3; ++z) sred[z][wave] = ws[z];
    }
    float gs[3];
#pragma unroll
    for (int z = 0; z < 3; ++z) {
        gs[z] = e[z];
#pragma unroll
        for (int off = 1; off <= 16; off <<= 1)
            gs[z] += __shfl_xor(gs[z], off);
    }
    __syncthreads();
    float total[3];
#pragma unroll
    for (int z = 0; z < 3; ++z)
        total[z] = sred[z][0] + sred[z][1] + sred[z][2] + sred[z][3];
    if ((n & 31) == 0) {
#pragma unroll
        for (int z = 0; z < 3; ++z) gred[z][n >> 5] = gs[z] / total[z];
    }
    __syncthreads();

    float gv[3][8];
#pragma unroll
    for (int z = 0; z < 3; ++z) {
        float tot = 0.f;
#pragma unroll
        for (int m = 0; m < 8; ++m) tot += gred[z][m];
        float inv = 1.0f / (tot + 1e-8f);
#pragma unroll
        for (int m = 0; m < 8; ++m) gv[z][m] = gred[z][m] * inv;
    }

    const int r0 = n & 127;
    const int half = n >> 7;
    const bf16* src_qk = allh + (size_t)t * 1024;
    const bf16* src_v  = allh + (size_t)NT * DD + (size_t)t * 1024;
    float hq = 0.f, hk = 0.f, hv = 0.f;
#pragma unroll
    for (int m = 0; m < 8; ++m) {
        float aqk = __bfloat162float(src_qk[m * 128 + r0]);
        float av  = __bfloat162float(src_v[m * 128 + r0]);
        hq += aqk * gv[0][m];
        hk += aqk * gv[1][m];
        hv += av  * gv[2][m];
    }
    __syncthreads();   // all allh_v reads complete before in-place preV writes
#pragma unroll
    for (int mm = 0; mm < 4; ++mm) {
        int m = half * 4 + mm;
        size_t o = (size_t)t * 1024 + m * 128 + r0;
        preQ[o] = __float2bfloat16(hq * gv[0][m]);
        preK[o] = __float2bfloat16(hk * gv[1][m]);
        preV[o] = __float2bfloat16(hv * gv[2][m]);
    }
}

// -------------------- Flash attention, split-kt (MFMA) --------------------
#define LDK 68   // padded halfword stride for K/V/P LDS tiles

__global__ __launch_bounds__(256) void flash_attn_split(
    const bf16* __restrict__ Q, const bf16* __restrict__ K,
    const bf16* __restrict__ V, float* __restrict__ Opart,
    float* __restrict__ ml) {
    const int bx = blockIdx.x;
    const int c = bx & 511;
    const int second = bx >> 9;
    const int qt = second ? (c >> 5) : (15 - (c >> 5));
    const int half = second;
    const int bh = c & 31;
    const int b = bh >> 4;
    const int h = bh & 15;
    const int h0 = (qt + 2) >> 1;
    const int kt_lo = half ? h0 : 0;
    const int kt_hi = half ? (qt + 1) : h0;

    const int tid = threadIdx.x;
    const int wave = tid >> 6;
    const int lane = tid & 63;
    const int quad = lane >> 4;
    const int l15 = lane & 15;

    __shared__ short Ks[64 * LDK];        // Ks[kr][dh]
    __shared__ short Vt[64 * LDK];        // Vt[dh][kr]
    __shared__ short Ps[4 * 16 * LDK];    // per-wave P[m][kr]

    const int q_row = qt * 64 + wave * 16 + l15;
    const bf16* qptr = Q + (size_t)(b * SS + q_row) * DD + h * DH + quad * 8;
    short8 aq0 = *(const short8*)qptr;
    short8 aq1 = *(const short8*)(qptr + 32);

    float m_r[4], l_r[4];
    f32x4 o[4];
#pragma unroll
    for (int r = 0; r < 4; ++r) { m_r[r] = -3.0e38f; l_r[r] = 0.f; }
#pragma unroll
    for (int cc = 0; cc < 4; ++cc) o[cc] = (f32x4)0.f;

    const float scale = 0.125f;

    for (int kt = kt_lo; kt < kt_hi; ++kt) {
        const int kt0 = kt * 64;
        __syncthreads();
        {
            const int kr = tid >> 2;
            const int dhb = (tid & 3) * 16;
            const bf16* src = K + (size_t)(b * SS + kt0 + kr) * DD + h * DH + dhb;
            short4v v0 = *(const short4v*)(src);
            short4v v1 = *(const short4v*)(src + 4);
            short4v v2 = *(const short4v*)(src + 8);
            short4v v3 = *(const short4v*)(src + 12);
            short* dst = &Ks[kr * LDK + dhb];
            *(short4v*)(dst) = v0;
            *(short4v*)(dst + 4) = v1;
            *(short4v*)(dst + 8) = v2;
            *(short4v*)(dst + 12) = v3;
        }
        {
            const int krp = tid & 31;
            const int dhb = (tid >> 5) * 8;
            const bf16* s0 = V + (size_t)(b * SS + kt0 + 2 * krp) * DD + h * DH + dhb;
            short8 r0 = *(const short8*)s0;
            short8 r1 = *(const short8*)(s0 + DD);
#pragma unroll
            for (int i = 0; i < 8; ++i) {
                unsigned int pk = (unsigned short)r0[i] | ((unsigned int)(unsigned short)r1[i] << 16);
                *(unsigned int*)&Vt[(dhb + i) * LDK + 2 * krp] = pk;
            }
        }
        __syncthreads();

        f32x4 s[4];
#pragma unroll
        for (int cc = 0; cc < 4; ++cc) {
            short8 bk0 = lds_load8(&Ks[(cc * 16 + l15) * LDK + quad * 8]);
            short8 bk1 = lds_load8(&Ks[(cc * 16 + l15) * LDK + 32 + quad * 8]);
            f32x4 acc = (f32x4)0.f;
            acc = __builtin_amdgcn_mfma_f32_16x16x32_bf16(aq0, bk0, acc, 0, 0, 0);
            acc = __builtin_amdgcn_mfma_f32_16x16x32_bf16(aq1, bk1, acc, 0, 0, 0);
            s[cc] = acc;
        }

        const bool diag = (kt == qt);
#pragma unroll
        for (int cc = 0; cc < 4; ++cc) {
#pragma unroll
            for (int r = 0; r < 4; ++r) {
                float v = s[cc][r] * scale;
                if (diag) {
                    int row_rel = wave * 16 + quad * 4 + r;
                    int col_rel = cc * 16 + l15;
                    if (col_rel > row_rel) v = -3.0e38f;
                }
                s[cc][r] = v;
            }
        }

        float p[4][4];
        float alpha[4];
#pragma unroll
        for (int r = 0; r < 4; ++r) {
            float mx = fmaxf(fmaxf(s[0][r], s[1][r]), fmaxf(s[2][r], s[3][r]));
            mx = fmaxf(mx, __shfl_xor(mx, 1));
            mx = fmaxf(mx, __shfl_xor(mx, 2));
            mx = fmaxf(mx, __shfl_xor(mx, 4));
            mx = fmaxf(mx, __shfl_xor(mx, 8));
            float new_m = fmaxf(m_r[r], mx);
            alpha[r] = __expf(m_r[r] - new_m);
            float rs = 0.f;
#pragma unroll
            for (int cc = 0; cc < 4; ++cc) {
                float e = __expf(s[cc][r] - new_m);
                p[cc][r] = e;
                rs += e;
            }
            rs += __shfl_xor(rs, 1);
            rs += __shfl_xor(rs, 2);
            rs += __shfl_xor(rs, 4);
            rs += __shfl_xor(rs, 8);
            l_r[r] = l_r[r] * alpha[r] + rs;
            m_r[r] = new_m;
        }
#pragma unroll
        for (int cc = 0; cc < 4; ++cc)
#pragma unroll
            for (int r = 0; r < 4; ++r) o[cc][r] *= alpha[r];

        // P: C-layout -> wave-private LDS slab -> A-layout (no barrier needed)
        short* pw = &Ps[wave * 16 * LDK];
#pragma unroll
        for (int cc = 0; cc < 4; ++cc)
#pragma unroll
            for (int r = 0; r < 4; ++r) {
                bf16 hb = __float2bfloat16(p[cc][r]);
                pw[(quad * 4 + r) * LDK + cc * 16 + l15] = *(short*)&hb;
            }

        short8 ap0 = lds_load8(&pw[l15 * LDK + quad * 8]);
        short8 ap1 = lds_load8(&pw[l15 * LDK + 32 + quad * 8]);

#pragma unroll
        for (int cc = 0; cc < 4; ++cc) {
            short8 bv0 = lds_load8(&Vt[(cc * 16 + l15) * LDK + quad * 8]);
            short8 bv1 = lds_load8(&Vt[(cc * 16 + l15) * LDK + 32 + quad * 8]);
            o[cc] = __builtin_amdgcn_mfma_f32_16x16x32_bf16(ap0, bv0, o[cc], 0, 0, 0);
            o[cc] = __builtin_amdgcn_mfma_f32_16x16x32_bf16(ap1, bv1, o[cc], 0, 0, 0);
        }
    }

    // ---- write partials (unnormalized O, m, l) ----
    const int idx = (half * 32 + bh) * 16 + qt;
    float* ob = Opart + (size_t)idx * 4096;
#pragma unroll
    for (int cc = 0; cc < 4; ++cc)
#pragma unroll
        for (int r = 0; r < 4; ++r) {
            int row = wave * 16 + quad * 4 + r;
            ob[row * 64 + cc * 16 + l15] = o[cc][r];
        }
    if (l15 == 0) {
#pragma unroll
        for (int r = 0; r < 4; ++r) {
            int row = wave * 16 + quad * 4 + r;
            ml[(size_t)idx * 128 + row] = m_r[r];
            ml[(size_t)idx * 128 + 64 + row] = l_r[r];
        }
    }
}

// Merge the two kt-halves: out = (O0*w0 + O1*w1) / (l0*w0 + l1*w1).
__global__ void attn_combine(const float* __restrict__ Opart,
                             const float* __restrict__ ml,
                             bf16* __restrict__ out) {
    const int bidx = blockIdx.x;       // 512 = bh*16 + qt
    const int bh = bidx >> 4;
    const int qt = bidx & 15;
    const int b = bh >> 4;
    const int h = bh & 15;
    const int tid = threadIdx.x;       // 256
    const int row = tid >> 2;
    const int cg = tid & 3;

    const int p0 = bh * 16 + qt;
    const int p1 = 512 + bh * 16 + qt;
    float m0 = ml[(size_t)p0 * 128 + row], l0 = ml[(size_t)p0 * 128 + 64 + row];
    float m1 = ml[(size_t)p1 * 128 + row], l1 = ml[(size_t)p1 * 128 + 64 + row];
    float ms = fmaxf(m0, m1);
    float w0 = __expf(m0 - ms), w1 = __expf(m1 - ms);
    float inv = 1.0f / (l0 * w0 + l1 * w1);

    const float* o0 = Opart + (size_t)p0 * 4096 + row * 64 + cg * 16;
    const float* o1 = Opart + (size_t)p1 * 4096 + row * 64 + cg * 16;
    short out16[16];
#pragma unroll
    for (int j = 0; j < 16; j += 4) {
        float4 a = *(const float4*)(o0 + j);
        float4 bb = *(const float4*)(o1 + j);
        float v0 = (a.x * w0 + bb.x * w1) * inv;
        float v1 = (a.y * w0 + bb.y * w1) * inv;
        float v2 = (a.z * w0 + bb.z * w1) * inv;
        float v3 = (a.w * w0 + bb.w * w1) * inv;
        bf16 t0 = __float2bfloat16(v0); out16[j] = *(short*)&t0;
        bf16 t1 = __float2bfloat16(v1); out16[j + 1] = *(short*)&t1;
        bf16 t2 = __float2bfloat16(v2); out16[j + 2] = *(short*)&t2;
        bf16 t3 = __float2bfloat16(v3); out16[j + 3] = *(short*)&t3;
    }
    short* dst = (short*)(out + (size_t)(b * SS + qt * 64 + row) * DD + h * DH + cg * 16);
    *(short8*)dst = *(short8*)&out16[0];
    *(short8*)(dst + 8) = *(short8*)&out16[8];
}

extern "C" void kernel_launch(void* const* d_in, const int* in_sizes, int n_in,
                              void* d_out, int out_size, void* d_ws, size_t ws_size,
                              hipStream_t stream) {
    const float* x    = (const float*)d_in[0];
    const float* qk_f = (const float*)d_in[1];
    const float* qk_r = (const float*)d_in[2];
    const float* v_f  = (const float*)d_in[3];
    const float* v_r  = (const float*)d_in[4];
    const float* Wg_q = (const float*)d_in[5];
    const float* Wg_k = (const float*)d_in[6];
    const float* Wg_v = (const float*)d_in[7];
    const float* W_O  = (const float*)d_in[8];

    // Workspace (256 MiB). Layout:
    //  0..4    xb      -> preQ      -> attnb
    //  4..8    wg_bt(4..5.5)+pad    -> preK
    //  5.5..9.5 fbt    (dead after proj)
    //  8..12           -> Kb
    //  9.5..12.5 logits (dead after gate_combine)
    //  12..16          -> Vb
    //  16..18 qkr_bt | 18..20 vr_bt | 20..22 wo_bt (stable)
    //  32..48 Opart (f32 partials) | 48..48.5 ml
    // d_out: allh [0..8 MiB] -> preV in-place over allh_v -> Qb [0..4] -> f32 out
    char* w = (char*)d_ws;
    const size_t MB = 1 << 20;
    bf16* xb     = (bf16*)(w + 0);
    bf16* wg_bt  = (bf16*)(w + 4 * MB);
    bf16* fbt    = (bf16*)(w + (size_t)(5.5 * MB));
    bf16* logits = (bf16*)(w + (size_t)(9.5 * MB));
    bf16* qkr_bt = (bf16*)(w + 16 * MB);
    bf16* vr_bt  = (bf16*)(w + 18 * MB);
    bf16* wo_bt  = (bf16*)(w + 20 * MB);
    bf16* preQ   = (bf16*)(w + 0);
    bf16* preK   = (bf16*)(w + 4 * MB);
    bf16* Kb     = (bf16*)(w + 8 * MB);
    bf16* Vb     = (bf16*)(w + 12 * MB);
    bf16* attnb  = (bf16*)(w + 0);
    float* Opart = (float*)(w + 32 * MB);     // 1024 * 4096 f32 = 16 MiB
    float* mlbuf = (float*)(w + 48 * MB);     // 1024 * 128 f32 = 0.5 MiB
    bf16* allh   = (bf16*)d_out;              // [2][2048][1024] bf16 = 8 MiB
    bf16* preV   = allh + (size_t)NT * DD;    // in-place over allh_v
    bf16* Qb     = (bf16*)d_out;              // over dead allh_qk
    float* out   = (float*)d_out;

    // 1) convert/transpose all inputs to bf16 (weights -> Bt[N][K])
    ConvJobs J;
    J.src[0] = qk_f; J.dst[0] = fbt;              J.K[0] = 1024; J.R[0] = 128;  J.G[0] = 8;
    J.src[1] = v_f;  J.dst[1] = fbt + 1024*1024;  J.K[1] = 1024; J.R[1] = 128;  J.G[1] = 8;
    J.src[2] = qk_r; J.dst[2] = qkr_bt;           J.K[2] = 1024; J.R[2] = 1024; J.G[2] = 1;
    J.src[3] = v_r;  J.dst[3] = vr_bt;            J.K[3] = 1024; J.R[3] = 1024; J.G[3] = 1;
    J.src[4] = W_O;  J.dst[4] = wo_bt;            J.K[4] = 1024; J.R[4] = 1024; J.G[4] = 1;
    J.src[5] = Wg_q; J.dst[5] = wg_bt;            J.K[5] = 1024; J.R[5] = 256;  J.G[5] = 1;
    J.src[6] = Wg_k; J.dst[6] = wg_bt + 256*1024; J.K[6] = 1024; J.R[6] = 256;  J.G[6] = 1;
    J.src[7] = Wg_v; J.dst[7] = wg_bt + 2*256*1024; J.K[7] = 1024; J.R[7] = 256; J.G[7] = 1;
    J.src[8] = x;    J.dst[8] = xb;               J.K[8] = 0;    J.R[8] = 0;    J.G[8] = 0;
    int tiles[9] = {1024, 1024, 1024, 1024, 1024, 256, 256, 256, 512};
    int cum = 0;
    for (int i = 0; i < 9; ++i) { cum += tiles[i]; J.tEnd[i] = cum; }
    convert_kernel<<<cum, 256, 0, stream>>>(J);

    // 2) all projections in ONE launch (z=5)
    GemmZ Pp;
    Pp.A[0] = Pp.A[1] = Pp.A[2] = Pp.A[3] = Pp.A[4] = xb;
    Pp.Bt[0] = fbt;             Pp.Bt[1] = fbt + 1024*1024;
    Pp.Bt[2] = wg_bt;           Pp.Bt[3] = wg_bt + 256*1024;  Pp.Bt[4] = wg_bt + 2*256*1024;
    Pp.C[0] = allh;             Pp.C[1] = allh + (size_t)NT * DD;
    Pp.C[2] = logits;           Pp.C[3] = logits + (size_t)NT * NN;
    Pp.C[4] = logits + 2 * (size_t)NT * NN;
    Pp.N[0] = 1024; Pp.N[1] = 1024; Pp.N[2] = 256; Pp.N[3] = 256; Pp.N[4] = 256;
    mfma_gemm_64z<bf16, 0><<<dim3(8, 32, 5), 256, 0, stream>>>(Pp, DD);

    // 3) fused gates + combine + make_pre (shuffle softmax; preV in-place)
    gate_combine<<<NT, 256, 0, stream>>>(logits, allh, preQ, preK, preV);

    // 4) restore Q,K,V in ONE launch (z=3)
    GemmZ Pr;
    Pr.A[0] = preQ; Pr.A[1] = preK; Pr.A[2] = preV;
    Pr.Bt[0] = qkr_bt; Pr.Bt[1] = qkr_bt; Pr.Bt[2] = vr_bt;
    Pr.C[0] = Qb; Pr.C[1] = Kb; Pr.C[2] = Vb;
    Pr.N[0] = Pr.N[1] = Pr.N[2] = 1024;
    Pr.A[3] = Pr.A[4] = nullptr; Pr.Bt[3] = Pr.Bt[4] = nullptr;
    Pr.C[3] = Pr.C[4] = nullptr; Pr.N[3] = Pr.N[4] = 0;
    mfma_gemm_64z<bf16, 1><<<dim3(8, 32, 3), 256, 0, stream>>>(Pr, DD);

    // 5) flash attention split-kt (1024 blocks, critical path 8 iters)
    flash_attn_split<<<dim3(1024), 256, 0, stream>>>(Qb, Kb, Vb, Opart, mlbuf);

    // 6) merge halves -> attnb
    attn_combine<<<dim3(512), 256, 0, stream>>>(Opart, mlbuf, attnb);

    // 7) out = attnb @ W_O (f32 into d_out; Qb dead after flash)
    mfma_gemm_64<float><<<dim3(8, 32), 256, 0, stream>>>(attnb, wo_bt, out, DD, DD);
}

// Round 10
// 195.931 us; speedup vs baseline: 1.1540x; 1.0507x over previous
//
#include <hip/hip_runtime.h>
#include <hip/hip_bf16.h>

// Problem constants
#define BB 2
#define SS 1024
#define DD 1024
#define NH 16
#define DH 64
#define MM 8
#define RR 128
#define NN 256
#define NT (BB*SS)          // 2048 tokens

using bf16 = __hip_bfloat16;

typedef __attribute__((ext_vector_type(8))) short short8;   // 8 bf16 (4 VGPRs) MFMA A/B frag
typedef __attribute__((ext_vector_type(4))) short short4v;  // 8-byte unit
typedef __attribute__((ext_vector_type(4))) float f32x4;    // MFMA C/D frag

__device__ __forceinline__ void stf(float* p, size_t i, float v) { p[i] = v; }
__device__ __forceinline__ void stf(bf16* p, size_t i, float v) { p[i] = __float2bfloat16(v); }

// async 16B global->LDS (lane i lands at ldsbase + i*16; ldsbase wave-uniform)
#define GLD16(g, l) __builtin_amdgcn_global_load_lds( \
    (const __attribute__((address_space(1))) void*)(g), \
    (__attribute__((address_space(3))) void*)(l), 16, 0, 0)

// Load 8 bf16 (as shorts) from LDS via two 8B reads (base only 8B-aligned).
__device__ __forceinline__ short8 lds_load8(const short* p) {
    short4v a = *(const short4v*)p;
    short4v b = *(const short4v*)(p + 4);
    short8 r;
    r[0] = a[0]; r[1] = a[1]; r[2] = a[2]; r[3] = a[3];
    r[4] = b[0]; r[5] = b[1]; r[6] = b[2]; r[7] = b[3];
    return r;
}

// ---------------- shared MFMA GEMM body: 64x128 tile, BK=64 ----------------
// C[M,N] = A[M,K] @ Bt[N,K]^T, bf16 K-major. 4 waves (2x2), wave = 32x64
// (2x4 16x16x32 frags), 16 MFMA per barrier pair. LDS 24 KB.
// Chunk = 16B = 8 bf16; slot = chunk ^ ((row>>1)&7) XOR swizzle -> frag
// ds_read_b128 is 2-way bank-aliased (free, m136).
template <typename TC>
__device__ __forceinline__ void gemm64_body(
    const bf16* __restrict__ A, const bf16* __restrict__ Bt, TC* __restrict__ C,
    int Kdim, int Nz, int m0, int n0, bf16* As, bf16* Bs) {
    const int tid = threadIdx.x;
    const int wave = tid >> 6, lane = tid & 63;
    const int quad = lane >> 4, l15 = lane & 15;
    const int wr = wave >> 1, wc = wave & 1;

    f32x4 acc[2][4];
#pragma unroll
    for (int i = 0; i < 2; ++i)
#pragma unroll
        for (int j = 0; j < 4; ++j) acc[i][j] = (f32x4)0.f;

    for (int k0 = 0; k0 < Kdim; k0 += 64) {
        __syncthreads();
#pragma unroll
        for (int i = 0; i < 2; ++i) {   // A: 512 chunks
            const int L = i * 256 + wave * 64 + lane;
            const int row = L >> 3;
            const int gch = (L & 7) ^ ((row >> 1) & 7);
            GLD16(A + (size_t)(m0 + row) * Kdim + k0 + gch * 8, &As[(i * 256 + wave * 64) * 8]);
        }
#pragma unroll
        for (int i = 0; i < 4; ++i) {   // B: 1024 chunks
            const int L = i * 256 + wave * 64 + lane;
            const int row = L >> 3;
            const int gch = (L & 7) ^ ((row >> 1) & 7);
            GLD16(Bt + (size_t)(n0 + row) * Kdim + k0 + gch * 8, &Bs[(i * 256 + wave * 64) * 8]);
        }
        __syncthreads();   // vmcnt(0): tiles resident

#pragma unroll
        for (int kk = 0; kk < 2; ++kk) {
            short8 aF[2], bF[4];
#pragma unroll
            for (int bi = 0; bi < 2; ++bi) {
                int m = wr * 32 + bi * 16 + l15;
                int slot = (kk * 4 + quad) ^ ((m >> 1) & 7);
                aF[bi] = *(const short8*)&As[(m * 8 + slot) * 8];
            }
#pragma unroll
            for (int bj = 0; bj < 4; ++bj) {
                int n = wc * 64 + bj * 16 + l15;
                int slot = (kk * 4 + quad) ^ ((n >> 1) & 7);
                bF[bj] = *(const short8*)&Bs[(n * 8 + slot) * 8];
            }
#pragma unroll
            for (int bi = 0; bi < 2; ++bi)
#pragma unroll
                for (int bj = 0; bj < 4; ++bj)
                    acc[bi][bj] = __builtin_amdgcn_mfma_f32_16x16x32_bf16(aF[bi], bF[bj], acc[bi][bj], 0, 0, 0);
        }
    }

#pragma unroll
    for (int bi = 0; bi < 2; ++bi)
#pragma unroll
        for (int bj = 0; bj < 4; ++bj)
#pragma unroll
            for (int r = 0; r < 4; ++r) {
                int row = m0 + wr * 32 + bi * 16 + quad * 4 + r;
                int col = n0 + wc * 64 + bj * 16 + l15;
                stf(C, (size_t)row * Nz + col, acc[bi][bj][r]);
            }
}

struct GemmZ {
    const bf16* A[5];
    const bf16* Bt[5];
    void* C[5];
    int N[5];
};

// Projections: flat 704-block grid (no no-op blocks).
// blocks 0..511: z = b>>8 (N=1024, 8x32 tiles); 512..703: z = 2+(b-512)/64
// (N=256, 2x32 tiles).
__global__ __launch_bounds__(256) void mfma_proj(GemmZ P, int Kdim) {
    __shared__ bf16 As[64 * 64];
    __shared__ bf16 Bs[128 * 64];
    const int bidx = blockIdx.x;
    int z, xx, yy;
    if (bidx < 512) { z = bidx >> 8; int r = bidx & 255; yy = r >> 3; xx = r & 7; }
    else { int r = bidx - 512; z = 2 + r / 64; r = r % 64; yy = r >> 1; xx = r & 1; }
    gemm64_body<bf16>(P.A[z], P.Bt[z], (bf16*)P.C[z], Kdim, P.N[z], yy * 64, xx * 128, As, Bs);
}

// Restore Q,K,V: 3-D grid (8,32,3), all useful.
__global__ __launch_bounds__(256) void mfma_restore(GemmZ P, int Kdim) {
    __shared__ bf16 As[64 * 64];
    __shared__ bf16 Bs[128 * 64];
    const int z = blockIdx.z;
    gemm64_body<bf16>(P.A[z], P.Bt[z], (bf16*)P.C[z], Kdim, P.N[z],
                      blockIdx.y * 64, blockIdx.x * 128, As, Bs);
}

// W_O: single job, f32 output.
__global__ __launch_bounds__(256) void mfma_gemm_64(
    const bf16* __restrict__ A, const bf16* __restrict__ Bt, float* __restrict__ C,
    int Kdim, int Ndim) {
    __shared__ bf16 As[64 * 64];
    __shared__ bf16 Bs[128 * 64];
    gemm64_body<float>(A, Bt, C, Kdim, Ndim, blockIdx.y * 64, blockIdx.x * 128, As, Bs);
}

// ---------------- fused convert/transpose (f32 -> bf16) ----------------
struct ConvJobs {
    const float* src[9];
    bf16* dst[9];
    int K[9], R[9], G[9];
    int tEnd[9];   // cumulative tile counts
};

__global__ void convert_kernel(ConvJobs J) {
    __shared__ float tile[32][33];
    const int b = blockIdx.x;
    int j = 0;
    while (j < 8 && b >= J.tEnd[j]) ++j;
    const int local = b - (j > 0 ? J.tEnd[j - 1] : 0);
    const float* src = J.src[j];
    bf16* dst = J.dst[j];
    const int tid = threadIdx.x;

    if (J.G[j] == 0) {
        size_t base = (size_t)local * 4096 + (size_t)tid * 16;
        const float4* s4 = (const float4*)(src + base);
        short* d = (short*)(dst + base);
#pragma unroll
        for (int c = 0; c < 4; ++c) {
            float4 v = s4[c];
            short4v o;
            bf16 t0 = __float2bfloat16(v.x); o[0] = *(short*)&t0;
            bf16 t1 = __float2bfloat16(v.y); o[1] = *(short*)&t1;
            bf16 t2 = __float2bfloat16(v.z); o[2] = *(short*)&t2;
            bf16 t3 = __float2bfloat16(v.w); o[3] = *(short*)&t3;
            *(short4v*)(d + c * 4) = o;
        }
    } else {
        const int Kj = J.K[j], Rj = J.R[j];
        const int Rb = Rj >> 5, Kb = Kj >> 5;
        const int perG = Kb * Rb;
        const int g = local / perG;
        const int rem = local - g * perG;
        const int kb = rem / Rb, rb = rem - kb * Rb;
        const int tx = tid & 31, ty0 = tid >> 5;
        const float* s = src + ((size_t)(g * Kj + kb * 32) * Rj) + rb * 32 + tx;
#pragma unroll
        for (int p = 0; p < 4; ++p)
            tile[ty0 + p * 8][tx] = s[(size_t)(ty0 + p * 8) * Rj];
        __syncthreads();
        bf16* dd = dst + ((size_t)(g * Rj + rb * 32) * Kj) + kb * 32 + tx;
#pragma unroll
        for (int p = 0; p < 4; ++p)
            dd[(size_t)(ty0 + p * 8) * Kj] = __float2bfloat16(tile[tx][ty0 + p * 8]);
    }
}

// ---------------- fused gates + combine + make_pre (shuffle softmax) -------
__global__ void gate_combine(const bf16* __restrict__ logitsAll,
                             const bf16* __restrict__ allh,
                             bf16* __restrict__ preQ, bf16* __restrict__ preK,
                             bf16* __restrict__ preV) {
    const int t = blockIdx.x;
    const int n = threadIdx.x;   // 256
    const int wave = n >> 6, lane = n & 63;
    __shared__ float wred[3][4];
    __shared__ float sred[3][4];
    __shared__ float gred[3][8];

    float v[3], e[3];
#pragma unroll
    for (int z = 0; z < 3; ++z)
        v[z] = __bfloat162float(logitsAll[(size_t)z * NT * NN + (size_t)t * NN + n]);

    float mz[3];
#pragma unroll
    for (int z = 0; z < 3; ++z) {
        mz[z] = v[z];
#pragma unroll
        for (int off = 1; off <= 32; off <<= 1)
            mz[z] = fmaxf(mz[z], __shfl_xor(mz[z], off));
    }
    if (lane == 0) {
#pragma unroll
        for (int z = 0; z < 3; ++z) wred[z][wave] = mz[z];
    }
    __syncthreads();
    float gmax[3];
#pragma unroll
    for (int z = 0; z < 3; ++z)
        gmax[z] = fmaxf(fmaxf(wred[z][0], wred[z][1]), fmaxf(wred[z][2], wred[z][3]));

    float ws[3];
#pragma unroll
    for (int z = 0; z < 3; ++z) {
        e[z] = __expf(v[z] - gmax[z]);
        ws[z] = e[z];
#pragma unroll
        for (int off = 1; off <= 32; off <<= 1)
            ws[z] += __shfl_xor(ws[z], off);
    }
    if (lane == 0) {
#pragma unroll
        for (int z = 0; z < 3; ++z) sred[z][wave] = ws[z];
    }
    float gs[3];
#pragma unroll
    for (int z = 0; z < 3; ++z) {
        gs[z] = e[z];
#pragma unroll
        for (int off = 1; off <= 16; off <<= 1)
            gs[z] += __shfl_xor(gs[z], off);
    }
    __syncthreads();
    float total[3];
#pragma unroll
    for (int z = 0; z < 3; ++z)
        total[z] = sred[z][0] + sred[z][1] + sred[z][2] + sred[z][3];
    if ((n & 31) == 0) {
#pragma unroll
        for (int z = 0; z < 3; ++z) gred[z][n >> 5] = gs[z] / total[z];
    }
    __syncthreads();

    float gv[3][8];
#pragma unroll
    for (int z = 0; z < 3; ++z) {
        float tot = 0.f;
#pragma unroll
        for (int m = 0; m < 8; ++m) tot += gred[z][m];
        float inv = 1.0f / (tot + 1e-8f);
#pragma unroll
        for (int m = 0; m < 8; ++m) gv[z][m] = gred[z][m] * inv;
    }

    const int r0 = n & 127;
    const int half = n >> 7;
    const bf16* src_qk = allh + (size_t)t * 1024;
    const bf16* src_v  = allh + (size_t)NT * DD + (size_t)t * 1024;
    float hq = 0.f, hk = 0.f, hv = 0.f;
#pragma unroll
    for (int m = 0; m < 8; ++m) {
        float aqk = __bfloat162float(src_qk[m * 128 + r0]);
        float av  = __bfloat162float(src_v[m * 128 + r0]);
        hq += aqk * gv[0][m];
        hk += aqk * gv[1][m];
        hv += av  * gv[2][m];
    }
    __syncthreads();   // all allh_v reads complete before in-place preV writes
#pragma unroll
    for (int mm = 0; mm < 4; ++mm) {
        int m = half * 4 + mm;
        size_t o = (size_t)t * 1024 + m * 128 + r0;
        preQ[o] = __float2bfloat16(hq * gv[0][m]);
        preK[o] = __float2bfloat16(hk * gv[1][m]);
        preV[o] = __float2bfloat16(hv * gv[2][m]);
    }
}

// -------------- Flash attention, split-kt, software-pipelined --------------
// Per iteration: issue next K-tile GLD16s + next V global loads FIRST, then
// compute the current tile (MFMA+softmax), then pack/ds_write the V prefetch,
// then ONE barrier (its vmcnt drain overlaps with the whole compute phase).
// K staged GLD16 + XOR swizzle (16B ds_read_b128 frags, 2-way = free);
// V staged transposed via packed-u32 (LDK=68 padding).
#define LDK 68

__global__ __launch_bounds__(256) void flash_attn_split(
    const bf16* __restrict__ Q, const bf16* __restrict__ K,
    const bf16* __restrict__ V, float* __restrict__ Opart,
    float* __restrict__ ml) {
    const int bx = blockIdx.x;
    const int c = bx & 511;
    const int second = bx >> 9;
    const int qt = second ? (c >> 5) : (15 - (c >> 5));
    const int half = second;
    const int bh = c & 31;
    const int b = bh >> 4;
    const int h = bh & 15;
    const int h0 = (qt + 2) >> 1;
    const int kt_lo = half ? h0 : 0;
    const int kt_hi = half ? (qt + 1) : h0;

    const int tid = threadIdx.x;
    const int wave = tid >> 6;
    const int lane = tid & 63;
    const int quad = lane >> 4;
    const int l15 = lane & 15;

    __shared__ short Ks[2][64 * 64];      // 16 KB, GLD16 + XOR swizzle
    __shared__ short Vt[2][64 * LDK];     // 17 KB, transposed
    __shared__ short Ps[4 * 16 * LDK];    // per-wave P[m][kr]

    const int q_row = qt * 64 + wave * 16 + l15;
    const bf16* qptr = Q + (size_t)(b * SS + q_row) * DD + h * DH + quad * 8;
    short8 aq0 = *(const short8*)qptr;
    short8 aq1 = *(const short8*)(qptr + 32);

    // V staging geometry (per thread)
    const int krp = tid & 31;
    const int dhb = (tid >> 5) * 8;

    float m_r[4], l_r[4];
    f32x4 o[4];
#pragma unroll
    for (int r = 0; r < 4; ++r) { m_r[r] = -3.0e38f; l_r[r] = 0.f; }
#pragma unroll
    for (int cc = 0; cc < 4; ++cc) o[cc] = (f32x4)0.f;

    const float scale = 0.125f;

    // ---- prologue: stage first tile into buf 0 ----
    if (kt_lo < kt_hi) {
#pragma unroll
        for (int i = 0; i < 2; ++i) {
            const int L = i * 256 + wave * 64 + lane;
            const int row = L >> 3;
            const int gch = (L & 7) ^ ((row >> 1) & 7);
            GLD16(K + (size_t)(b * SS + kt_lo * 64 + row) * DD + h * DH + gch * 8,
                  &Ks[0][(i * 256 + wave * 64) * 8]);
        }
        const bf16* s0 = V + (size_t)(b * SS + kt_lo * 64 + 2 * krp) * DD + h * DH + dhb;
        short8 r0 = *(const short8*)s0;
        short8 r1 = *(const short8*)(s0 + DD);
#pragma unroll
        for (int i = 0; i < 8; ++i) {
            unsigned int pk = (unsigned short)r0[i] | ((unsigned int)(unsigned short)r1[i] << 16);
            *(unsigned int*)&Vt[0][(dhb + i) * LDK + 2 * krp] = pk;
        }
        __syncthreads();
    }

    for (int kt = kt_lo; kt < kt_hi; ++kt) {
        const int buf = (kt - kt_lo) & 1;
        const bool pf = (kt + 1 < kt_hi);
        short8 pr0, pr1;
        if (pf) {
            // issue next K tile (async direct-to-LDS) and next V loads (VGPR)
#pragma unroll
            for (int i = 0; i < 2; ++i) {
                const int L = i * 256 + wave * 64 + lane;
                const int row = L >> 3;
                const int gch = (L & 7) ^ ((row >> 1) & 7);
                GLD16(K + (size_t)(b * SS + (kt + 1) * 64 + row) * DD + h * DH + gch * 8,
                      &Ks[buf ^ 1][(i * 256 + wave * 64) * 8]);
            }
            const bf16* s0 = V + (size_t)(b * SS + (kt + 1) * 64 + 2 * krp) * DD + h * DH + dhb;
            pr0 = *(const short8*)s0;
            pr1 = *(const short8*)(s0 + DD);
        }

        // ---- compute current tile ----
        const short* KsB = Ks[buf];
        f32x4 s[4];
#pragma unroll
        for (int cc = 0; cc < 4; ++cc) {
            int n = cc * 16 + l15;
            int sl0 = quad ^ ((n >> 1) & 7);
            int sl1 = (quad + 4) ^ ((n >> 1) & 7);
            short8 bk0 = *(const short8*)&KsB[(n * 8 + sl0) * 8];
            short8 bk1 = *(const short8*)&KsB[(n * 8 + sl1) * 8];
            f32x4 acc = (f32x4)0.f;
            acc = __builtin_amdgcn_mfma_f32_16x16x32_bf16(aq0, bk0, acc, 0, 0, 0);
            acc = __builtin_amdgcn_mfma_f32_16x16x32_bf16(aq1, bk1, acc, 0, 0, 0);
            s[cc] = acc;
        }

        const bool diag = (kt == qt);
#pragma unroll
        for (int cc = 0; cc < 4; ++cc) {
#pragma unroll
            for (int r = 0; r < 4; ++r) {
                float v = s[cc][r] * scale;
                if (diag) {
                    int row_rel = wave * 16 + quad * 4 + r;
                    int col_rel = cc * 16 + l15;
                    if (col_rel > row_rel) v = -3.0e38f;
                }
                s[cc][r] = v;
            }
        }

        float p[4][4];
        float alpha[4];
#pragma unroll
        for (int r = 0; r < 4; ++r) {
            float mx = fmaxf(fmaxf(s[0][r], s[1][r]), fmaxf(s[2][r], s[3][r]));
            mx = fmaxf(mx, __shfl_xor(mx, 1));
            mx = fmaxf(mx, __shfl_xor(mx, 2));
            mx = fmaxf(mx, __shfl_xor(mx, 4));
            mx = fmaxf(mx, __shfl_xor(mx, 8));
            float new_m = fmaxf(m_r[r], mx);
            alpha[r] = __expf(m_r[r] - new_m);
            float rs = 0.f;
#pragma unroll
            for (int cc = 0; cc < 4; ++cc) {
                float e = __expf(s[cc][r] - new_m);
                p[cc][r] = e;
                rs += e;
            }
            rs += __shfl_xor(rs, 1);
            rs += __shfl_xor(rs, 2);
            rs += __shfl_xor(rs, 4);
            rs += __shfl_xor(rs, 8);
            l_r[r] = l_r[r] * alpha[r] + rs;
            m_r[r] = new_m;
        }
#pragma unroll
        for (int cc = 0; cc < 4; ++cc)
#pragma unroll
            for (int r = 0; r < 4; ++r) o[cc][r] *= alpha[r];

        // P: C-layout -> wave-private LDS slab -> A-layout (no barrier needed)
        short* pw = &Ps[wave * 16 * LDK];
#pragma unroll
        for (int cc = 0; cc < 4; ++cc)
#pragma unroll
            for (int r = 0; r < 4; ++r) {
                bf16 hb = __float2bfloat16(p[cc][r]);
                pw[(quad * 4 + r) * LDK + cc * 16 + l15] = *(short*)&hb;
            }

        short8 ap0 = lds_load8(&pw[l15 * LDK + quad * 8]);
        short8 ap1 = lds_load8(&pw[l15 * LDK + 32 + quad * 8]);

        const short* VtB = Vt[buf];
#pragma unroll
        for (int cc = 0; cc < 4; ++cc) {
            short8 bv0 = lds_load8(&VtB[(cc * 16 + l15) * LDK + quad * 8]);
            short8 bv1 = lds_load8(&VtB[(cc * 16 + l15) * LDK + 32 + quad * 8]);
            o[cc] = __builtin_amdgcn_mfma_f32_16x16x32_bf16(ap0, bv0, o[cc], 0, 0, 0);
            o[cc] = __builtin_amdgcn_mfma_f32_16x16x32_bf16(ap1, bv1, o[cc], 0, 0, 0);
        }

        // ---- write V prefetch into the other buffer, then the ONE barrier ----
        if (pf) {
#pragma unroll
            for (int i = 0; i < 8; ++i) {
                unsigned int pk = (unsigned short)pr0[i] | ((unsigned int)(unsigned short)pr1[i] << 16);
                *(unsigned int*)&Vt[buf ^ 1][(dhb + i) * LDK + 2 * krp] = pk;
            }
        }
        __syncthreads();
    }

    // ---- write partials (unnormalized O, m, l) ----
    const int idx = (half * 32 + bh) * 16 + qt;
    float* ob = Opart + (size_t)idx * 4096;
#pragma unroll
    for (int cc = 0; cc < 4; ++cc)
#pragma unroll
        for (int r = 0; r < 4; ++r) {
            int row = wave * 16 + quad * 4 + r;
            ob[row * 64 + cc * 16 + l15] = o[cc][r];
        }
    if (l15 == 0) {
#pragma unroll
        for (int r = 0; r < 4; ++r) {
            int row = wave * 16 + quad * 4 + r;
            ml[(size_t)idx * 128 + row] = m_r[r];
            ml[(size_t)idx * 128 + 64 + row] = l_r[r];
        }
    }
}

// Merge the two kt-halves: out = (O0*w0 + O1*w1) / (l0*w0 + l1*w1).
__global__ void attn_combine(const float* __restrict__ Opart,
                             const float* __restrict__ ml,
                             bf16* __restrict__ out) {
    const int bidx = blockIdx.x;       // 512 = bh*16 + qt
    const int bh = bidx >> 4;
    const int qt = bidx & 15;
    const int b = bh >> 4;
    const int h = bh & 15;
    const int tid = threadIdx.x;       // 256
    const int row = tid >> 2;
    const int cg = tid & 3;

    const int p0 = bh * 16 + qt;
    const int p1 = 512 + bh * 16 + qt;
    float m0 = ml[(size_t)p0 * 128 + row], l0 = ml[(size_t)p0 * 128 + 64 + row];
    float m1 = ml[(size_t)p1 * 128 + row], l1 = ml[(size_t)p1 * 128 + 64 + row];
    float ms = fmaxf(m0, m1);
    float w0 = __expf(m0 - ms), w1 = __expf(m1 - ms);
    float inv = 1.0f / (l0 * w0 + l1 * w1);

    const float* o0 = Opart + (size_t)p0 * 4096 + row * 64 + cg * 16;
    const float* o1 = Opart + (size_t)p1 * 4096 + row * 64 + cg * 16;
    short out16[16];
#pragma unroll
    for (int j = 0; j < 16; j += 4) {
        float4 a = *(const float4*)(o0 + j);
        float4 bb = *(const float4*)(o1 + j);
        float v0 = (a.x * w0 + bb.x * w1) * inv;
        float v1 = (a.y * w0 + bb.y * w1) * inv;
        float v2 = (a.z * w0 + bb.z * w1) * inv;
        float v3 = (a.w * w0 + bb.w * w1) * inv;
        bf16 t0 = __float2bfloat16(v0); out16[j] = *(short*)&t0;
        bf16 t1 = __float2bfloat16(v1); out16[j + 1] = *(short*)&t1;
        bf16 t2 = __float2bfloat16(v2); out16[j + 2] = *(short*)&t2;
        bf16 t3 = __float2bfloat16(v3); out16[j + 3] = *(short*)&t3;
    }
    short* dst = (short*)(out + (size_t)(b * SS + qt * 64 + row) * DD + h * DH + cg * 16);
    *(short8*)dst = *(short8*)&out16[0];
    *(short8*)(dst + 8) = *(short8*)&out16[8];
}

extern "C" void kernel_launch(void* const* d_in, const int* in_sizes, int n_in,
                              void* d_out, int out_size, void* d_ws, size_t ws_size,
                              hipStream_t stream) {
    const float* x    = (const float*)d_in[0];
    const float* qk_f = (const float*)d_in[1];
    const float* qk_r = (const float*)d_in[2];
    const float* v_f  = (const float*)d_in[3];
    const float* v_r  = (const float*)d_in[4];
    const float* Wg_q = (const float*)d_in[5];
    const float* Wg_k = (const float*)d_in[6];
    const float* Wg_v = (const float*)d_in[7];
    const float* W_O  = (const float*)d_in[8];

    // Workspace (256 MiB). Layout:
    //  0..4    xb      -> preQ      -> attnb
    //  4..8    wg_bt(4..5.5)+pad    -> preK
    //  5.5..9.5 fbt    (dead after proj)
    //  8..12           -> Kb
    //  9.5..12.5 logits (dead after gate_combine)
    //  12..16          -> Vb
    //  16..18 qkr_bt | 18..20 vr_bt | 20..22 wo_bt (stable)
    //  32..48 Opart (f32 partials) | 48..48.5 ml
    // d_out: allh [0..8 MiB] -> preV in-place over allh_v -> Qb [0..4] -> f32 out
    char* w = (char*)d_ws;
    const size_t MB = 1 << 20;
    bf16* xb     = (bf16*)(w + 0);
    bf16* wg_bt  = (bf16*)(w + 4 * MB);
    bf16* fbt    = (bf16*)(w + (size_t)(5.5 * MB));
    bf16* logits = (bf16*)(w + (size_t)(9.5 * MB));
    bf16* qkr_bt = (bf16*)(w + 16 * MB);
    bf16* vr_bt  = (bf16*)(w + 18 * MB);
    bf16* wo_bt  = (bf16*)(w + 20 * MB);
    bf16* preQ   = (bf16*)(w + 0);
    bf16* preK   = (bf16*)(w + 4 * MB);
    bf16* Kb     = (bf16*)(w + 8 * MB);
    bf16* Vb     = (bf16*)(w + 12 * MB);
    bf16* attnb  = (bf16*)(w + 0);
    float* Opart = (float*)(w + 32 * MB);     // 1024 * 4096 f32 = 16 MiB
    float* mlbuf = (float*)(w + 48 * MB);     // 1024 * 128 f32 = 0.5 MiB
    bf16* allh   = (bf16*)d_out;              // [2][2048][1024] bf16 = 8 MiB
    bf16* preV   = allh + (size_t)NT * DD;    // in-place over allh_v
    bf16* Qb     = (bf16*)d_out;              // over dead allh_qk
    float* out   = (float*)d_out;

    // 1) convert/transpose all inputs to bf16 (weights -> Bt[N][K])
    ConvJobs J;
    J.src[0] = qk_f; J.dst[0] = fbt;              J.K[0] = 1024; J.R[0] = 128;  J.G[0] = 8;
    J.src[1] = v_f;  J.dst[1] = fbt + 1024*1024;  J.K[1] = 1024; J.R[1] = 128;  J.G[1] = 8;
    J.src[2] = qk_r; J.dst[2] = qkr_bt;           J.K[2] = 1024; J.R[2] = 1024; J.G[2] = 1;
    J.src[3] = v_r;  J.dst[3] = vr_bt;            J.K[3] = 1024; J.R[3] = 1024; J.G[3] = 1;
    J.src[4] = W_O;  J.dst[4] = wo_bt;            J.K[4] = 1024; J.R[4] = 1024; J.G[4] = 1;
    J.src[5] = Wg_q; J.dst[5] = wg_bt;            J.K[5] = 1024; J.R[5] = 256;  J.G[5] = 1;
    J.src[6] = Wg_k; J.dst[6] = wg_bt + 256*1024; J.K[6] = 1024; J.R[6] = 256;  J.G[6] = 1;
    J.src[7] = Wg_v; J.dst[7] = wg_bt + 2*256*1024; J.K[7] = 1024; J.R[7] = 256; J.G[7] = 1;
    J.src[8] = x;    J.dst[8] = xb;               J.K[8] = 0;    J.R[8] = 0;    J.G[8] = 0;
    int tiles[9] = {1024, 1024, 1024, 1024, 1024, 256, 256, 256, 512};
    int cum = 0;
    for (int i = 0; i < 9; ++i) { cum += tiles[i]; J.tEnd[i] = cum; }
    convert_kernel<<<cum, 256, 0, stream>>>(J);

    // 2) all projections in ONE flat launch (704 useful blocks, no no-ops)
    GemmZ Pp;
    Pp.A[0] = Pp.A[1] = Pp.A[2] = Pp.A[3] = Pp.A[4] = xb;
    Pp.Bt[0] = fbt;             Pp.Bt[1] = fbt + 1024*1024;
    Pp.Bt[2] = wg_bt;           Pp.Bt[3] = wg_bt + 256*1024;  Pp.Bt[4] = wg_bt + 2*256*1024;
    Pp.C[0] = allh;             Pp.C[1] = allh + (size_t)NT * DD;
    Pp.C[2] = logits;           Pp.C[3] = logits + (size_t)NT * NN;
    Pp.C[4] = logits + 2 * (size_t)NT * NN;
    Pp.N[0] = 1024; Pp.N[1] = 1024; Pp.N[2] = 256; Pp.N[3] = 256; Pp.N[4] = 256;
    mfma_proj<<<dim3(704), 256, 0, stream>>>(Pp, DD);

    // 3) fused gates + combine + make_pre (shuffle softmax; preV in-place)
    gate_combine<<<NT, 256, 0, stream>>>(logits, allh, preQ, preK, preV);

    // 4) restore Q,K,V in ONE launch (z=3, 768 blocks)
    GemmZ Pr;
    Pr.A[0] = preQ; Pr.A[1] = preK; Pr.A[2] = preV;
    Pr.Bt[0] = qkr_bt; Pr.Bt[1] = qkr_bt; Pr.Bt[2] = vr_bt;
    Pr.C[0] = Qb; Pr.C[1] = Kb; Pr.C[2] = Vb;
    Pr.N[0] = Pr.N[1] = Pr.N[2] = 1024;
    Pr.A[3] = Pr.A[4] = nullptr; Pr.Bt[3] = Pr.Bt[4] = nullptr;
    Pr.C[3] = Pr.C[4] = nullptr; Pr.N[3] = Pr.N[4] = 0;
    mfma_restore<<<dim3(8, 32, 3), 256, 0, stream>>>(Pr, DD);

    // 5) flash attention split-kt, software-pipelined (1024 blocks)
    flash_attn_split<<<dim3(1024), 256, 0, stream>>>(Qb, Kb, Vb, Opart, mlbuf);

    // 6) merge halves -> attnb
    attn_combine<<<dim3(512), 256, 0, stream>>>(Opart, mlbuf, attnb);

    // 7) out = attnb @ W_O (f32 into d_out; Qb dead after flash)
    mfma_gemm_64<<<dim3(8, 32), 256, 0, stream>>>(attnb, wo_bt, out, DD, DD);
}